// Round 6
// baseline (300.881 us; speedup 1.0000x reference)
//
#include <hip/hip_runtime.h>

using bf16 = __bf16;
typedef bf16 bf16x4 __attribute__((ext_vector_type(4)));
typedef bf16 bf16x8 __attribute__((ext_vector_type(8)));
typedef float f32x4 __attribute__((ext_vector_type(4)));
typedef float f32x8 __attribute__((ext_vector_type(8)));

#define MFMA16(a, b, c) __builtin_amdgcn_mfma_f32_16x16x32_bf16(a, b, c, 0, 0, 0)

constexpr int Bb = 4, Tt = 2048, Dd = 1024, Hh = 16, Hd = 64;
constexpr int Mrows = Bb * Tt;                 // 8192
constexpr float CEXP = 0.18033688011112042f;   // (1/sqrt(64)) * log2(e), folded into Wq/bq

// async global->LDS, 16B per lane; LDS dst = wave-uniform base + lane*16 [m97/m104]
__device__ __forceinline__ void gload_lds16(const bf16* g, bf16* lds_base) {
  __builtin_amdgcn_global_load_lds((const __attribute__((address_space(1))) void*)g,
                                   (__attribute__((address_space(3))) void*)lds_base,
                                   16, 0, 0);
}

// ---------------------------------------------------------------- cast x -> bf16
__global__ void cast_f32_bf16_kernel(const float* __restrict__ in, bf16* __restrict__ out) {
  size_t i = ((size_t)blockIdx.x * 256 + threadIdx.x) * 8;
  f32x8 v = *(const f32x8*)(in + i);
  *(bf16x8*)(out + i) = __builtin_convertvector(v, bf16x8);
}

// ---- fused transpose+cast of all four weight matrices: W[k][n] f32 -> Wt[n][k] bf16
__global__ void transpose_cast_w4_kernel(const float* __restrict__ Wq, const float* __restrict__ Wk,
                                         const float* __restrict__ Wv, const float* __restrict__ Wo,
                                         bf16* __restrict__ Wt, bf16* __restrict__ Wot) {
  __shared__ alignas(16) float tile[64][68];
  const int tid = threadIdx.x;
  const int n0 = blockIdx.x * 64, k0 = blockIdx.y * 64, z = blockIdx.z;
  const float* W = (z == 0) ? Wq : (z == 1) ? Wk : (z == 2) ? Wv : Wo;
  bf16* dst = (z == 3) ? Wot : (Wt + (size_t)z * Dd * Dd);
  const float scale = (z == 0) ? CEXP : 1.0f;
#pragma unroll
  for (int it = 0; it < 4; ++it) {
    int chunk = tid + it * 256;        // 1024 chunks: 64 k-rows x 16 float4
    int kr = chunk >> 4, c4 = chunk & 15;
    f32x4 v = *(const f32x4*)(W + (size_t)(k0 + kr) * Dd + n0 + c4 * 4);
    *(f32x4*)&tile[kr][c4 * 4] = v * scale;
  }
  __syncthreads();
#pragma unroll
  for (int it = 0; it < 2; ++it) {
    int chunk = tid + it * 256;        // 512 chunks: 64 n-rows x 8 bf16x8
    int n = chunk & 63, k8 = chunk >> 6;
    bf16x8 o;
#pragma unroll
    for (int j = 0; j < 8; ++j) o[j] = (bf16)tile[k8 * 8 + j][n];
    *(bf16x8*)(dst + (size_t)(n0 + n) * Dd + k0 + k8 * 8) = o;
  }
}

// ---------------------------------------------------------------- pack qkv bias
__global__ void pack_bias_kernel(const float* __restrict__ bq, const float* __restrict__ bk,
                                 const float* __restrict__ bv, float* __restrict__ outb) {
  int i = blockIdx.x * 256 + threadIdx.x;   // 0..3071
  float v = (i < 1024) ? bq[i] * CEXP : (i < 2048 ? bk[i - 1024] : bv[i - 2048]);
  outb[i] = v;
}

// --------- GEMM (m97 structure): C = A @ Bt^T + bias. 128x128 tile, BK=64,
// global_load_lds width=16 staging into UNPADDED [128][64] LDS (contiguity required
// by wave-uniform-base+lane*16; lane l -> row l>>3, chunk l&7: (l>>3)*64+(l&7)*8 = l*8).
template <typename OutT>
__global__ __launch_bounds__(256)
void gemm_bf16_kernel(const bf16* __restrict__ A, const bf16* __restrict__ Bt,
                      const float* __restrict__ bias, OutT* __restrict__ C,
                      int M, int N, int K) {
  __shared__ alignas(16) bf16 As[128 * 64];
  __shared__ alignas(16) bf16 Bs[128 * 64];
  const int tid = threadIdx.x;
  const int lane = tid & 63, wave = tid >> 6;
  const int col = lane & 15, quad = lane >> 4;
  const int wr = (wave >> 1) * 64, wc = (wave & 1) * 64;
  const size_t m0 = (size_t)blockIdx.x * 128, n0 = (size_t)blockIdx.y * 128;
  const int srow = lane >> 3, schunk = (lane & 7) * 8;   // staging map within a wave-call

  f32x4 acc[4][4];
#pragma unroll
  for (int i = 0; i < 4; ++i)
#pragma unroll
    for (int j = 0; j < 4; ++j)
#pragma unroll
      for (int r = 0; r < 4; ++r) acc[i][j][r] = 0.f;

  for (int k0 = 0; k0 < K; k0 += 64) {
#pragma unroll
    for (int it = 0; it < 4; ++it) {
      int rbase = it * 32 + wave * 8;                    // 8 rows per wave-call
      gload_lds16(A + (m0 + rbase + srow) * (size_t)K + k0 + schunk, &As[rbase * 64]);
      gload_lds16(Bt + (n0 + rbase + srow) * (size_t)K + k0 + schunk, &Bs[rbase * 64]);
    }
    __syncthreads();                                     // compiler drains vmcnt here
#pragma unroll
    for (int kk = 0; kk < 2; ++kk) {
      bf16x8 af[4], bfr[4];
#pragma unroll
      for (int i = 0; i < 4; ++i) af[i] = *(const bf16x8*)&As[(wr + i * 16 + col) * 64 + kk * 32 + quad * 8];
#pragma unroll
      for (int j = 0; j < 4; ++j) bfr[j] = *(const bf16x8*)&Bs[(wc + j * 16 + col) * 64 + kk * 32 + quad * 8];
#pragma unroll
      for (int i = 0; i < 4; ++i)
#pragma unroll
        for (int j = 0; j < 4; ++j) acc[i][j] = MFMA16(af[i], bfr[j], acc[i][j]);
    }
    __syncthreads();
  }
#pragma unroll
  for (int i = 0; i < 4; ++i)
#pragma unroll
    for (int j = 0; j < 4; ++j) {
      size_t row = m0 + wr + i * 16 + quad * 4;
      size_t c = n0 + wc + j * 16 + col;
      float bv = bias[c];
#pragma unroll
      for (int r = 0; r < 4; ++r) C[(row + r) * (size_t)N + c] = (OutT)(acc[i][j][r] + bv);
    }
}

// --------------------------- V transpose: QKV V-part [t][d] -> Vt[b][h][d][t] bf16
__global__ void transpose_v_kernel(const bf16* __restrict__ qkv, bf16* __restrict__ vt) {
  __shared__ alignas(16) bf16 tile[64][72];   // [d][t]
  const int tid = threadIdx.x;
  const int t0 = blockIdx.x * 64;
  const int h = blockIdx.y, b = blockIdx.z;
  const bf16* src = qkv + (size_t)(b * Tt + t0) * 3072 + 2048 + h * Hd;
#pragma unroll
  for (int it = 0; it < 2; ++it) {
    int chunk = tid + it * 256;
    int tr = chunk >> 3, d8 = chunk & 7;
    bf16x8 v = *(const bf16x8*)(src + (size_t)tr * 3072 + d8 * 8);
#pragma unroll
    for (int j = 0; j < 8; ++j) tile[d8 * 8 + j][tr] = v[j];
  }
  __syncthreads();
  bf16* dst = vt + ((size_t)(b * Hh + h) * Hd) * Tt + t0;
#pragma unroll
  for (int it = 0; it < 2; ++it) {
    int chunk = tid + it * 256;
    int d = chunk >> 3, t8 = chunk & 7;
    bf16x8 o = *(const bf16x8*)&tile[d][t8 * 8];
    *(bf16x8*)(dst + (size_t)d * Tt + t8 * 8) = o;
  }
}

// ----------------------------------------------- flash attention, 256 Q-rows/block
// Grid 512 = 2 blocks/CU (no tail). 4 waves x 64 Q-rows (t=0..3). Transposed algebra
// (S^T = MFMA(kf,qf), O^T = MFMA(vf,pf)); K/V double-buffered in XOR-swizzled LDS
// (manual staging kept: flash is LDS-bound and the swizzle keeps reads ~conflict-free;
// global_load_lds would force an unswizzled layout with 16-way read conflicts).
// This rev: pbuf per-(wave,t) -> ONE lgkmcnt(0) drain per iter (was 4).
__global__ __launch_bounds__(256, 2)
void flash_attn_kernel(const bf16* __restrict__ qkv, const bf16* __restrict__ vt,
                       const unsigned char* __restrict__ mask, bf16* __restrict__ ao) {
  __shared__ alignas(16) bf16 Ks[2][64 * 64];      // [key][slot^], 8KB each
  __shared__ alignas(16) bf16 Vs[2][64 * 64];      // [d][slot^]
  __shared__ alignas(16) bf16 pbuf[4][4][16 * 64]; // [wave][t][query][slot^], 32KB

  const int tid = threadIdx.x;
  const int wave = tid >> 6, lane = tid & 63;
  const int col = lane & 15, quad = lane >> 4;
  const int id = blockIdx.x;
  const int hb = id & 63, qi2 = id >> 6;           // id%8 -> XCD pinning per (b,h)
  const int h = hb & 15, b = hb >> 4;
  const int qbase0 = qi2 * 256 + wave * 64;

  const bf16* Qp = qkv + (size_t)(b * Tt) * 3072 + h * Hd;
  const bf16* Kp = Qp + 1024;
  const bf16* Vp = vt + ((size_t)(b * Hh + h) * Hd) * Tt;
  const unsigned char* mp = mask + b * Tt;

  // mask any-nonzero flags for the 32 key-blocks via ballot
  unsigned long long anym;
  {
    const unsigned long long* mq = (const unsigned long long*)mp;
    unsigned long long acc = 0;
#pragma unroll
    for (int j = 0; j < 4; ++j) acc |= mq[lane * 4 + j];
    anym = __ballot(acc != 0ull);
  }

  // Q fragments (pre-scaled by CEXP): free index = query
  bf16x8 qf[4][2];
#pragma unroll
  for (int t = 0; t < 4; ++t)
#pragma unroll
    for (int kk = 0; kk < 2; ++kk)
      qf[t][kk] = *(const bf16x8*)(Qp + (size_t)(qbase0 + t * 16 + col) * 3072 + kk * 32 + quad * 8);

  // staging map: row = lane, wave w stages 16B chunks {2w, 2w+1} of each row
  const bf16* Ksrc = Kp + (size_t)lane * 3072 + wave * 16;
  const bf16* Vsrc = Vp + (size_t)lane * Tt + wave * 16;
  const int ss1 = ((2 * wave) ^ (lane & 7)) * 8;
  const int ss2 = ((2 * wave + 1) ^ (lane & 7)) * 8;
  const int srowoff = lane * 64;

  {
    bf16x8 k0 = *(const bf16x8*)Ksrc, k1 = *(const bf16x8*)(Ksrc + 8);
    bf16x8 v0 = *(const bf16x8*)Vsrc, v1 = *(const bf16x8*)(Vsrc + 8);
    *(bf16x8*)&Ks[0][srowoff + ss1] = k0;  *(bf16x8*)&Ks[0][srowoff + ss2] = k1;
    *(bf16x8*)&Vs[0][srowoff + ss1] = v0;  *(bf16x8*)&Vs[0][srowoff + ss2] = v1;
  }
  __syncthreads();

  f32x4 oacc[4][4];
  float lsum[4];
#pragma unroll
  for (int t = 0; t < 4; ++t) {
    lsum[t] = 0.f;
#pragma unroll
    for (int n = 0; n < 4; ++n)
#pragma unroll
      for (int r = 0; r < 4; ++r) oacc[t][n][r] = 0.f;
  }

  const int fslot0 = ((0 * 4 + quad) ^ (col & 7)) * 8;
  const int fslot1 = ((1 * 4 + quad) ^ (col & 7)) * 8;

  for (int i = 0; i < 32; ++i) {
    const int cur = i & 1, nxt = cur ^ 1;
    const int kb = i * 64;

    // prefetch next K/V tile into registers (written to LDS before the barrier)
    bf16x8 nk0, nk1, nv0, nv1;
    if (i < 31) {
      const bf16* ks = Ksrc + (size_t)(kb + 64) * 3072;
      const bf16* vs = Vsrc + (kb + 64);
      nk0 = *(const bf16x8*)ks;  nk1 = *(const bf16x8*)(ks + 8);
      nv0 = *(const bf16x8*)vs;  nv1 = *(const bf16x8*)(vs + 8);
    }

    bf16x8 kf[4][2], vf[4][2];
#pragma unroll
    for (int kt = 0; kt < 4; ++kt) {
      kf[kt][0] = *(const bf16x8*)&Ks[cur][(kt * 16 + col) * 64 + fslot0];
      kf[kt][1] = *(const bf16x8*)&Ks[cur][(kt * 16 + col) * 64 + fslot1];
    }
#pragma unroll
    for (int n = 0; n < 4; ++n) {
      vf[n][0] = *(const bf16x8*)&Vs[cur][(n * 16 + col) * 64 + fslot0];
      vf[n][1] = *(const bf16x8*)&Vs[cur][(n * 16 + col) * 64 + fslot1];
    }

    // phase 1: S^T, mask, exp, pack, pbuf writes (all t) + VALU row-sums
    float rsv[4];
#pragma unroll
    for (int t = 0; t < 4; ++t) {
      f32x4 s[4];
#pragma unroll
      for (int kt = 0; kt < 4; ++kt)
#pragma unroll
        for (int r = 0; r < 4; ++r) s[kt][r] = 0.f;
#pragma unroll
      for (int kk = 0; kk < 2; ++kk)
#pragma unroll
        for (int kt = 0; kt < 4; ++kt) s[kt] = MFMA16(kf[kt][kk], qf[t][kk], s[kt]);

      if ((anym >> (2 * i)) & 3ull) {
#pragma unroll
        for (int kt = 0; kt < 4; ++kt)
#pragma unroll
          for (int r = 0; r < 4; ++r)
            if (mp[kb + kt * 16 + quad * 4 + r] != 0) s[kt][r] = -1e9f;
      }

      float rs = 0.f;
#pragma unroll
      for (int kt = 0; kt < 4; ++kt) {
        f32x4 pv;
#pragma unroll
        for (int r = 0; r < 4; ++r) {
          pv[r] = __builtin_amdgcn_exp2f(s[kt][r]);
          rs += pv[r];
        }
        bf16x4 pk = __builtin_convertvector(pv, bf16x4);   // packed cvt
        int slot = ((2 * kt + (quad >> 1)) ^ (col & 7)) * 8 + (quad & 1) * 4;
        *(bf16x4*)&pbuf[wave][t][col * 64 + slot] = pk;
      }
      rs += __shfl_xor(rs, 16, 64);
      rs += __shfl_xor(rs, 32, 64);
      rsv[t] = rs;
    }

    // phase 2: ONE drain, then all pf reads + O^T MFMAs
    __builtin_amdgcn_s_waitcnt(0xc07f);  // lgkmcnt(0)
#pragma unroll
    for (int t = 0; t < 4; ++t) {
      bf16x8 pf0 = *(const bf16x8*)&pbuf[wave][t][col * 64 + fslot0];
      bf16x8 pf1 = *(const bf16x8*)&pbuf[wave][t][col * 64 + fslot1];
#pragma unroll
      for (int n = 0; n < 4; ++n) {
        oacc[t][n] = MFMA16(vf[n][0], pf0, oacc[t][n]);
        oacc[t][n] = MFMA16(vf[n][1], pf1, oacc[t][n]);
      }
      lsum[t] += rsv[t];
    }

    if (i < 31) {
      *(bf16x8*)&Ks[nxt][srowoff + ss1] = nk0;  *(bf16x8*)&Ks[nxt][srowoff + ss2] = nk1;
      *(bf16x8*)&Vs[nxt][srowoff + ss1] = nv0;  *(bf16x8*)&Vs[nxt][srowoff + ss2] = nv1;
    }
    __syncthreads();
  }

  // epilogue: O^T col=query, row=d=n*16+quad*4+r -> packed bf16x4 stores
#pragma unroll
  for (int t = 0; t < 4; ++t) {
    float rl = 1.0f / lsum[t];
    size_t q = (size_t)b * Tt + qbase0 + t * 16 + col;
#pragma unroll
    for (int n = 0; n < 4; ++n) {
      bf16x4 ov;
#pragma unroll
      for (int r = 0; r < 4; ++r) ov[r] = (bf16)(oacc[t][n][r] * rl);
      *(bf16x4*)(ao + q * Dd + h * Hd + n * 16 + quad * 4) = ov;
    }
  }
}

// --------------------------------------------------------------------- launcher
extern "C" void kernel_launch(void* const* d_in, const int* in_sizes, int n_in,
                              void* d_out, int out_size, void* d_ws, size_t ws_size,
                              hipStream_t stream) {
  const float* x = (const float*)d_in[0];
  const unsigned char* mask = (const unsigned char*)d_in[1];
  const float* Wq = (const float*)d_in[2];
  const float* bq = (const float*)d_in[3];
  const float* Wk = (const float*)d_in[4];
  const float* bk = (const float*)d_in[5];
  const float* Wv = (const float*)d_in[6];
  const float* bv = (const float*)d_in[7];
  const float* Wo = (const float*)d_in[8];
  const float* bo = (const float*)d_in[9];
  float* out = (float*)d_out;

  char* ws = (char*)d_ws;
  size_t off = 0;
  auto alloc = [&](size_t bytes) {
    char* p = ws + off;
    off += (bytes + 255) & ~(size_t)255;
    return p;
  };
  bf16* xb  = (bf16*)alloc((size_t)Mrows * Dd * 2);        // 16.8MB (reused as AO)
  bf16* Wt  = (bf16*)alloc((size_t)3 * Dd * Dd * 2);       // 6.3MB  packed [3072][1024]
  bf16* Wot = (bf16*)alloc((size_t)Dd * Dd * 2);           // 2.1MB
  bf16* QKV = (bf16*)alloc((size_t)Mrows * 3 * Dd * 2);    // 50.3MB [8192][3072]
  bf16* Vt  = (bf16*)alloc((size_t)Bb * Hh * Hd * Tt * 2); // 16.8MB
  float* bqkv = (float*)alloc((size_t)3 * Dd * 4);

  cast_f32_bf16_kernel<<<Mrows * Dd / (256 * 8), 256, 0, stream>>>(x, xb);
  transpose_cast_w4_kernel<<<dim3(16, 16, 4), 256, 0, stream>>>(Wq, Wk, Wv, Wo, Wt, Wot);
  pack_bias_kernel<<<12, 256, 0, stream>>>(bq, bk, bv, bqkv);

  gemm_bf16_kernel<bf16><<<dim3(Mrows / 128, 3 * Dd / 128), 256, 0, stream>>>(
      xb, Wt, bqkv, QKV, Mrows, 3 * Dd, Dd);
  transpose_v_kernel<<<dim3(Tt / 64, Hh, Bb), 256, 0, stream>>>(QKV, Vt);

  bf16* AO = xb;  // xb dead after QKV GEMM
  flash_attn_kernel<<<dim3(512), 256, 0, stream>>>(QKV, Vt, mask, AO);
  gemm_bf16_kernel<float><<<dim3(Mrows / 128, Dd / 128), 256, 0, stream>>>(
      AO, Wot, bo, out, Mrows, Dd, Dd);
}

// Round 7
// 291.098 us; speedup vs baseline: 1.0336x; 1.0336x over previous
//
#include <hip/hip_runtime.h>

using bf16 = __bf16;
typedef bf16 bf16x4 __attribute__((ext_vector_type(4)));
typedef bf16 bf16x8 __attribute__((ext_vector_type(8)));
typedef float f32x4 __attribute__((ext_vector_type(4)));
typedef float f32x8 __attribute__((ext_vector_type(8)));

#define MFMA16(a, b, c) __builtin_amdgcn_mfma_f32_16x16x32_bf16(a, b, c, 0, 0, 0)

constexpr int Bb = 4, Tt = 2048, Dd = 1024, Hh = 16, Hd = 64;
constexpr int Mrows = Bb * Tt;                 // 8192
constexpr float CEXP = 0.18033688011112042f;   // (1/sqrt(64)) * log2(e), folded into Wq/bq

// async global->LDS, 16B per lane; LDS dst = wave-uniform base + lane*16 [m97/m104]
__device__ __forceinline__ void gload_lds16(const bf16* g, bf16* lds_base) {
  __builtin_amdgcn_global_load_lds((const __attribute__((address_space(1))) void*)g,
                                   (__attribute__((address_space(3))) void*)lds_base,
                                   16, 0, 0);
}

// ---------------------------------------------------------------- cast x -> bf16
__global__ void cast_f32_bf16_kernel(const float* __restrict__ in, bf16* __restrict__ out) {
  size_t i = ((size_t)blockIdx.x * 256 + threadIdx.x) * 8;
  f32x8 v = *(const f32x8*)(in + i);
  *(bf16x8*)(out + i) = __builtin_convertvector(v, bf16x8);
}

// ---- fused transpose+cast of all four weight matrices: W[k][n] f32 -> Wt[n][k] bf16
__global__ void transpose_cast_w4_kernel(const float* __restrict__ Wq, const float* __restrict__ Wk,
                                         const float* __restrict__ Wv, const float* __restrict__ Wo,
                                         bf16* __restrict__ Wt, bf16* __restrict__ Wot) {
  __shared__ alignas(16) float tile[64][68];
  const int tid = threadIdx.x;
  const int n0 = blockIdx.x * 64, k0 = blockIdx.y * 64, z = blockIdx.z;
  const float* W = (z == 0) ? Wq : (z == 1) ? Wk : (z == 2) ? Wv : Wo;
  bf16* dst = (z == 3) ? Wot : (Wt + (size_t)z * Dd * Dd);
  const float scale = (z == 0) ? CEXP : 1.0f;
#pragma unroll
  for (int it = 0; it < 4; ++it) {
    int chunk = tid + it * 256;
    int kr = chunk >> 4, c4 = chunk & 15;
    f32x4 v = *(const f32x4*)(W + (size_t)(k0 + kr) * Dd + n0 + c4 * 4);
    *(f32x4*)&tile[kr][c4 * 4] = v * scale;
  }
  __syncthreads();
#pragma unroll
  for (int it = 0; it < 2; ++it) {
    int chunk = tid + it * 256;
    int n = chunk & 63, k8 = chunk >> 6;
    bf16x8 o;
#pragma unroll
    for (int j = 0; j < 8; ++j) o[j] = (bf16)tile[k8 * 8 + j][n];
    *(bf16x8*)(dst + (size_t)(n0 + n) * Dd + k0 + k8 * 8) = o;
  }
}

// ---------------------------------------------------------------- pack qkv bias
__global__ void pack_bias_kernel(const float* __restrict__ bq, const float* __restrict__ bk,
                                 const float* __restrict__ bv, float* __restrict__ outb) {
  int i = blockIdx.x * 256 + threadIdx.x;
  float v = (i < 1024) ? bq[i] * CEXP : (i < 2048 ? bk[i - 1024] : bv[i - 2048]);
  outb[i] = v;
}

// --------- QKV GEMM (m97 staging) with fused V-transpose epilogue.
// C = xb @ Wt^T + bias over N=3072. Q/K blocks (n0<2048) -> QK[8192][2048];
// V blocks -> Vt[b][h][d][t] directly (4 acc regs = 4 consecutive t -> packed b64).
__global__ __launch_bounds__(256)
void gemm_qkv_kernel(const bf16* __restrict__ A, const bf16* __restrict__ Bt,
                     const float* __restrict__ bias, bf16* __restrict__ QK,
                     bf16* __restrict__ Vt) {
  constexpr int K = Dd, N = 3 * Dd;
  __shared__ alignas(16) bf16 As[128 * 64];
  __shared__ alignas(16) bf16 Bs[128 * 64];
  const int tid = threadIdx.x;
  const int lane = tid & 63, wave = tid >> 6;
  const int col = lane & 15, quad = lane >> 4;
  const int wr = (wave >> 1) * 64, wc = (wave & 1) * 64;
  const size_t m0 = (size_t)blockIdx.x * 128, n0 = (size_t)blockIdx.y * 128;
  const int srow = lane >> 3, schunk = (lane & 7) * 8;

  f32x4 acc[4][4];
#pragma unroll
  for (int i = 0; i < 4; ++i)
#pragma unroll
    for (int j = 0; j < 4; ++j)
#pragma unroll
      for (int r = 0; r < 4; ++r) acc[i][j][r] = 0.f;

  for (int k0 = 0; k0 < K; k0 += 64) {
#pragma unroll
    for (int it = 0; it < 4; ++it) {
      int rbase = it * 32 + wave * 8;
      gload_lds16(A + (m0 + rbase + srow) * (size_t)K + k0 + schunk, &As[rbase * 64]);
      gload_lds16(Bt + (n0 + rbase + srow) * (size_t)K + k0 + schunk, &Bs[rbase * 64]);
    }
    __syncthreads();
#pragma unroll
    for (int kk = 0; kk < 2; ++kk) {
      bf16x8 af[4], bfr[4];
#pragma unroll
      for (int i = 0; i < 4; ++i) af[i] = *(const bf16x8*)&As[(wr + i * 16 + col) * 64 + kk * 32 + quad * 8];
#pragma unroll
      for (int j = 0; j < 4; ++j) bfr[j] = *(const bf16x8*)&Bs[(wc + j * 16 + col) * 64 + kk * 32 + quad * 8];
#pragma unroll
      for (int i = 0; i < 4; ++i)
#pragma unroll
        for (int j = 0; j < 4; ++j) acc[i][j] = MFMA16(af[i], bfr[j], acc[i][j]);
    }
    __syncthreads();
  }

  if (n0 < 2048) {      // Q/K block -> compact [8192][2048] buffer
#pragma unroll
    for (int i = 0; i < 4; ++i)
#pragma unroll
      for (int j = 0; j < 4; ++j) {
        size_t row = m0 + wr + i * 16 + quad * 4;
        size_t c = n0 + wc + j * 16 + col;
        float bv = bias[c];
#pragma unroll
        for (int r = 0; r < 4; ++r) QK[(row + r) * 2048 + c] = (bf16)(acc[i][j][r] + bv);
      }
  } else {              // V block -> Vt[b][h][d][t], packed along t
#pragma unroll
    for (int i = 0; i < 4; ++i)
#pragma unroll
      for (int j = 0; j < 4; ++j) {
        size_t row = m0 + wr + i * 16 + quad * 4;
        int c = (int)(n0 + wc + j * 16 + col);
        float bv = bias[c];
        int dall = c - 2048, hh = dall >> 6, dd = dall & 63;
        int bi = (int)(row >> 11), trow = (int)(row & 2047);
        bf16x4 pk;
#pragma unroll
        for (int r = 0; r < 4; ++r) pk[r] = (bf16)(acc[i][j][r] + bv);
        *(bf16x4*)&Vt[((size_t)(bi * Hh + hh) * Hd + dd) * Tt + trow] = pk;
      }
  }
}

// ------------------------- generic GEMM (out-projection): C = A @ Bt^T + bias
__global__ __launch_bounds__(256)
void gemm_bf16_kernel(const bf16* __restrict__ A, const bf16* __restrict__ Bt,
                      const float* __restrict__ bias, float* __restrict__ C,
                      int M, int N, int K) {
  __shared__ alignas(16) bf16 As[128 * 64];
  __shared__ alignas(16) bf16 Bs[128 * 64];
  const int tid = threadIdx.x;
  const int lane = tid & 63, wave = tid >> 6;
  const int col = lane & 15, quad = lane >> 4;
  const int wr = (wave >> 1) * 64, wc = (wave & 1) * 64;
  const size_t m0 = (size_t)blockIdx.x * 128, n0 = (size_t)blockIdx.y * 128;
  const int srow = lane >> 3, schunk = (lane & 7) * 8;

  f32x4 acc[4][4];
#pragma unroll
  for (int i = 0; i < 4; ++i)
#pragma unroll
    for (int j = 0; j < 4; ++j)
#pragma unroll
      for (int r = 0; r < 4; ++r) acc[i][j][r] = 0.f;

  for (int k0 = 0; k0 < K; k0 += 64) {
#pragma unroll
    for (int it = 0; it < 4; ++it) {
      int rbase = it * 32 + wave * 8;
      gload_lds16(A + (m0 + rbase + srow) * (size_t)K + k0 + schunk, &As[rbase * 64]);
      gload_lds16(Bt + (n0 + rbase + srow) * (size_t)K + k0 + schunk, &Bs[rbase * 64]);
    }
    __syncthreads();
#pragma unroll
    for (int kk = 0; kk < 2; ++kk) {
      bf16x8 af[4], bfr[4];
#pragma unroll
      for (int i = 0; i < 4; ++i) af[i] = *(const bf16x8*)&As[(wr + i * 16 + col) * 64 + kk * 32 + quad * 8];
#pragma unroll
      for (int j = 0; j < 4; ++j) bfr[j] = *(const bf16x8*)&Bs[(wc + j * 16 + col) * 64 + kk * 32 + quad * 8];
#pragma unroll
      for (int i = 0; i < 4; ++i)
#pragma unroll
        for (int j = 0; j < 4; ++j) acc[i][j] = MFMA16(af[i], bfr[j], acc[i][j]);
    }
    __syncthreads();
  }
#pragma unroll
  for (int i = 0; i < 4; ++i)
#pragma unroll
    for (int j = 0; j < 4; ++j) {
      size_t row = m0 + wr + i * 16 + quad * 4;
      size_t c = n0 + wc + j * 16 + col;
      float bv = bias[c];
#pragma unroll
      for (int r = 0; r < 4; ++r) C[(row + r) * (size_t)N + c] = acc[i][j][r] + bv;
    }
}

// ----------------------------------------------- flash attention, register-resident P
// S^T = MFMA(kf, qf): lane (col=q, quad) holds keys kt*16+quad*4+r. k-permutation
// invariance: feed exp(S^T) DIRECTLY as the A operand of O = MFMA(pf, vf) with slot
// map sigma(kk,quad,j) = (2kk+(j>>2))*16 + quad*4 + (j&3); pf[kk] = concat of exp'd
// s[2kk], s[2kk+1] -- NO LDS round-trip for P. V is read from LDS with the same
// sigma (two b64 per frag). O lands row=q(quad*4+r), col=d; l (per q=col) is
// transposed once via tiny LDS at epilogue. Grid 512 = 2 blocks/CU, XCD-pinned.
__global__ __launch_bounds__(256, 2)
void flash_attn_kernel(const bf16* __restrict__ qk, const bf16* __restrict__ vt,
                       const unsigned char* __restrict__ mask, bf16* __restrict__ ao) {
  __shared__ alignas(16) bf16 Ks[2][64 * 64];      // [key][slot^], xor-swizzled 16B slots
  __shared__ alignas(16) bf16 Vs[2][64 * 64];      // [d][slot^]
  __shared__ alignas(16) float lred[4][64];        // per-wave l transpose

  const int tid = threadIdx.x;
  const int wave = tid >> 6, lane = tid & 63;
  const int col = lane & 15, quad = lane >> 4;
  const int id = blockIdx.x;
  const int hb = id & 63, qi2 = id >> 6;           // id%8 -> XCD pinning per (b,h)
  const int h = hb & 15, b = hb >> 4;
  const int qbase0 = qi2 * 256 + wave * 64;

  const bf16* Qp = qk + (size_t)(b * Tt) * 2048 + h * Hd;
  const bf16* Kp = Qp + 1024;
  const bf16* Vp = vt + ((size_t)(b * Hh + h) * Hd) * Tt;
  const unsigned char* mp = mask + b * Tt;

  unsigned long long anym;
  {
    const unsigned long long* mq = (const unsigned long long*)mp;
    unsigned long long acc = 0;
#pragma unroll
    for (int j = 0; j < 4; ++j) acc |= mq[lane * 4 + j];
    anym = __ballot(acc != 0ull);
  }

  // Q fragments (pre-scaled by CEXP): free index = query
  bf16x8 qf[4][2];
#pragma unroll
  for (int t = 0; t < 4; ++t)
#pragma unroll
    for (int kk = 0; kk < 2; ++kk)
      qf[t][kk] = *(const bf16x8*)(Qp + (size_t)(qbase0 + t * 16 + col) * 2048 + kk * 32 + quad * 8);

  // staging map: row = lane, wave w stages 16B chunks {2w, 2w+1} of each row
  const bf16* Ksrc = Kp + (size_t)lane * 2048 + wave * 16;
  const bf16* Vsrc = Vp + (size_t)lane * Tt + wave * 16;
  const int ss1 = ((2 * wave) ^ (lane & 7)) * 8;
  const int ss2 = ((2 * wave + 1) ^ (lane & 7)) * 8;
  const int srowoff = lane * 64;

  {
    bf16x8 k0 = *(const bf16x8*)Ksrc, k1 = *(const bf16x8*)(Ksrc + 8);
    bf16x8 v0 = *(const bf16x8*)Vsrc, v1 = *(const bf16x8*)(Vsrc + 8);
    *(bf16x8*)&Ks[0][srowoff + ss1] = k0;  *(bf16x8*)&Ks[0][srowoff + ss2] = k1;
    *(bf16x8*)&Vs[0][srowoff + ss1] = v0;  *(bf16x8*)&Vs[0][srowoff + ss2] = v1;
  }
  __syncthreads();

  f32x4 oacc[4][4];
  float lsum[4];
#pragma unroll
  for (int t = 0; t < 4; ++t) {
    lsum[t] = 0.f;
#pragma unroll
    for (int n = 0; n < 4; ++n)
#pragma unroll
      for (int r = 0; r < 4; ++r) oacc[t][n][r] = 0.f;
  }
  const f32x4 zero4 = {0.f, 0.f, 0.f, 0.f};

  const int fslot0 = ((0 * 4 + quad) ^ (col & 7)) * 8;   // b128 frag slots (kf)
  const int fslot1 = ((1 * 4 + quad) ^ (col & 7)) * 8;
  // sigma'd V b64 slots: elems kk*32 + 16*j2 + quad*4 -> chunk kk*4 + j2*2 + (quad>>1)
  const int voff = (quad & 1) * 4;
  const int vc00 = ((0 * 4 + 0 * 2 + (quad >> 1)) ^ 9999, 0);  // placeholder removed below

  for (int i = 0; i < 32; ++i) {
    const int cur = i & 1, nxt = cur ^ 1;
    const int kb = i * 64;

    bf16x8 nk0, nk1, nv0, nv1;
    if (i < 31) {
      const bf16* ks = Ksrc + (size_t)(kb + 64) * 2048;
      const bf16* vs = Vsrc + (kb + 64);
      nk0 = *(const bf16x8*)ks;  nk1 = *(const bf16x8*)(ks + 8);
      nv0 = *(const bf16x8*)vs;  nv1 = *(const bf16x8*)(vs + 8);
    }

    bf16x8 kf[4][2], vfs[4][2];
#pragma unroll
    for (int kt = 0; kt < 4; ++kt) {
      kf[kt][0] = *(const bf16x8*)&Ks[cur][(kt * 16 + col) * 64 + fslot0];
      kf[kt][1] = *(const bf16x8*)&Ks[cur][(kt * 16 + col) * 64 + fslot1];
    }
#pragma unroll
    for (int n = 0; n < 4; ++n) {
      const int row = (n * 16 + col) * 64;
      const int rx = col & 7;
#pragma unroll
      for (int kk = 0; kk < 2; ++kk) {
        bf16x4 lo = *(const bf16x4*)&Vs[cur][row + ((kk * 4 + 0 + (quad >> 1)) ^ rx) * 8 + voff];
        bf16x4 hi = *(const bf16x4*)&Vs[cur][row + ((kk * 4 + 2 + (quad >> 1)) ^ rx) * 8 + voff];
        vfs[n][kk] = __builtin_shufflevector(lo, hi, 0, 1, 2, 3, 4, 5, 6, 7);
      }
    }

#pragma unroll
    for (int t = 0; t < 4; ++t) {
      // S^T: col=query, row=key = kt*16+quad*4+r  (first MFMA takes C=0: no init movs)
      f32x4 s[4];
#pragma unroll
      for (int kt = 0; kt < 4; ++kt) s[kt] = MFMA16(kf[kt][0], qf[t][0], zero4);
#pragma unroll
      for (int kt = 0; kt < 4; ++kt) s[kt] = MFMA16(kf[kt][1], qf[t][1], s[kt]);

      if ((anym >> (2 * i)) & 3ull) {
#pragma unroll
        for (int kt = 0; kt < 4; ++kt)
#pragma unroll
          for (int r = 0; r < 4; ++r)
            if (mp[kb + kt * 16 + quad * 4 + r] != 0) s[kt][r] = -1e9f;
      }

      // P = exp2(S) stays in registers as the PV A-operand (sigma slot map)
      f32x4 e[4];
      float rs = 0.f;
#pragma unroll
      for (int kt = 0; kt < 4; ++kt)
#pragma unroll
        for (int r = 0; r < 4; ++r) {
          e[kt][r] = __builtin_amdgcn_exp2f(s[kt][r]);
          rs += e[kt][r];
        }
      bf16x4 c0 = __builtin_convertvector(e[0], bf16x4);
      bf16x4 c1 = __builtin_convertvector(e[1], bf16x4);
      bf16x4 c2 = __builtin_convertvector(e[2], bf16x4);
      bf16x4 c3 = __builtin_convertvector(e[3], bf16x4);
      bf16x8 pf0 = __builtin_shufflevector(c0, c1, 0, 1, 2, 3, 4, 5, 6, 7);
      bf16x8 pf1 = __builtin_shufflevector(c2, c3, 0, 1, 2, 3, 4, 5, 6, 7);
#pragma unroll
      for (int n = 0; n < 4; ++n) {
        oacc[t][n] = MFMA16(pf0, vfs[n][0], oacc[t][n]);
        oacc[t][n] = MFMA16(pf1, vfs[n][1], oacc[t][n]);
      }
      rs += __shfl_xor(rs, 16, 64);
      rs += __shfl_xor(rs, 32, 64);
      lsum[t] += rs;    // per query = t*16+col
    }

    if (i < 31) {
      *(bf16x8*)&Ks[nxt][srowoff + ss1] = nk0;  *(bf16x8*)&Ks[nxt][srowoff + ss2] = nk1;
      *(bf16x8*)&Vs[nxt][srowoff + ss1] = nv0;  *(bf16x8*)&Vs[nxt][srowoff + ss2] = nv1;
    }
    __syncthreads();
  }

  // epilogue: transpose l within wave (lsum indexed by col; O rows by quad*4+r)
  if (lane < 16) {
#pragma unroll
    for (int t = 0; t < 4; ++t) lred[wave][t * 16 + lane] = lsum[t];
  }
  __builtin_amdgcn_s_waitcnt(0xc07f);  // lgkmcnt(0), per-wave visibility
#pragma unroll
  for (int t = 0; t < 4; ++t) {
    f32x4 lv = *(const f32x4*)&lred[wave][t * 16 + quad * 4];
    f32x4 rl;
#pragma unroll
    for (int r = 0; r < 4; ++r) rl[r] = __builtin_amdgcn_rcpf(lv[r]);
#pragma unroll
    for (int n = 0; n < 4; ++n)
#pragma unroll
      for (int r = 0; r < 4; ++r) {
        size_t q = (size_t)b * Tt + qbase0 + t * 16 + quad * 4 + r;
        ao[q * Dd + h * Hd + n * 16 + col] = (bf16)(oacc[t][n][r] * rl[r]);
      }
  }
}

// --------------------------------------------------------------------- launcher
extern "C" void kernel_launch(void* const* d_in, const int* in_sizes, int n_in,
                              void* d_out, int out_size, void* d_ws, size_t ws_size,
                              hipStream_t stream) {
  const float* x = (const float*)d_in[0];
  const unsigned char* mask = (const unsigned char*)d_in[1];
  const float* Wq = (const float*)d_in[2];
  const float* bq = (const float*)d_in[3];
  const float* Wk = (const float*)d_in[4];
  const float* bk = (const float*)d_in[5];
  const float* Wv = (const float*)d_in[6];
  const float* bv = (const float*)d_in[7];
  const float* Wo = (const float*)d_in[8];
  const float* bo = (const float*)d_in[9];
  float* out = (float*)d_out;

  char* ws = (char*)d_ws;
  size_t off = 0;
  auto alloc = [&](size_t bytes) {
    char* p = ws + off;
    off += (bytes + 255) & ~(size_t)255;
    return p;
  };
  bf16* xb  = (bf16*)alloc((size_t)Mrows * Dd * 2);        // 16.8MB (reused as AO)
  bf16* Wt  = (bf16*)alloc((size_t)3 * Dd * Dd * 2);       // 6.3MB  packed [3072][1024]
  bf16* Wot = (bf16*)alloc((size_t)Dd * Dd * 2);           // 2.1MB
  bf16* QK  = (bf16*)alloc((size_t)Mrows * 2048 * 2);      // 33.6MB [8192][2048]
  bf16* Vt  = (bf16*)alloc((size_t)Bb * Hh * Hd * Tt * 2); // 16.8MB
  float* bqkv = (float*)alloc((size_t)3 * Dd * 4);

  cast_f32_bf16_kernel<<<Mrows * Dd / (256 * 8), 256, 0, stream>>>(x, xb);
  transpose_cast_w4_kernel<<<dim3(16, 16, 4), 256, 0, stream>>>(Wq, Wk, Wv, Wo, Wt, Wot);
  pack_bias_kernel<<<12, 256, 0, stream>>>(bq, bk, bv, bqkv);

  gemm_qkv_kernel<<<dim3(Mrows / 128, 3 * Dd / 128), 256, 0, stream>>>(
      xb, Wt, bqkv, QK, Vt);

  bf16* AO = xb;  // xb dead after QKV GEMM
  flash_attn_kernel<<<dim3(512), 256, 0, stream>>>(QK, Vt, mask, AO);
  gemm_bf16_kernel<<<dim3(Mrows / 128, Dd / 128), 256, 0, stream>>>(
      AO, Wot, bo, out, Mrows, Dd, Dd);
}